// Round 7
// baseline (572.175 us; speedup 1.0000x reference)
//
#include <hip/hip_runtime.h>

typedef short short8 __attribute__((ext_vector_type(8)));
typedef float f32x4 __attribute__((ext_vector_type(4)));

#define HID 96
#define WNUM 1664
#define NA_DIM 56
#define OUT_DIM 80
#define EPB 64
#define NT_TOT 104   // 1664/16
#define CHW 208      // cols per chunk
#define NCH 8
#define NTC 13       // n-tiles per chunk

#define N0f 0.158113883f      // 1/sqrt(40)
#define INV_S3 0.5773502692f  // 1/sqrt(3)
#define C_OUT1E 0.25f         // (1/sqrt(2))*(1/sqrt(8))

__device__ __forceinline__ unsigned short f2bf(float x) {
  unsigned u = __builtin_bit_cast(unsigned, x);
  u += 0x7FFFu + ((u >> 16) & 1u);
  return (unsigned short)(u >> 16);
}

// column permutation: new col J -> original W2 col
__device__ __forceinline__ int perm_col(int J) {
  int c = J / CHW, l = J - (J / CHW) * CHW;
  if (l < 128) { int vp = l >> 5, u = l & 31; return u * 32 + 4 * c + vp; }          // w1
  if (l < 160) { int u = l - 128; return 1024 + u * 8 + c; }                          // w2
  if (l < 168) { int u = l - 160; return 1280 + u * 8 + c; }                          // w3
  if (l < 200) { int q = l - 168; int vp = q >> 3, u = q & 7; return 1344 + u * 32 + 4 * c + vp; } // w4
  { int u = l - 200; return 1600 + u * 8 + c; }                                       // w5
}

__global__ __launch_bounds__(256) void zero_int_kernel(int* __restrict__ p, int n) {
  int i = blockIdx.x * 256 + threadIdx.x;
  if (i < n) p[i] = 0;
}

// ---------------- counting sort of edges by edge_src ----------------
__global__ __launch_bounds__(256) void hist_kernel(
    const int* __restrict__ edge_src, int* __restrict__ hist, int E) {
  int e = blockIdx.x * 256 + threadIdx.x;
  if (e < E) atomicAdd(&hist[edge_src[e]], 1);
}

__global__ __launch_bounds__(256) void scan1_kernel(
    const int* __restrict__ hist, int* __restrict__ excl,
    int* __restrict__ bsum, int n) {
  __shared__ int s[256];
  int t = threadIdx.x, i = blockIdx.x * 256 + t;
  int v = (i < n) ? hist[i] : 0;
  s[t] = v;
  __syncthreads();
  #pragma unroll
  for (int off = 1; off < 256; off <<= 1) {
    int tv = (t >= off) ? s[t - off] : 0;
    __syncthreads();
    s[t] += tv;
    __syncthreads();
  }
  if (i < n) excl[i] = s[t] - v;
  if (t == 255) bsum[blockIdx.x] = s[255];
}

__global__ __launch_bounds__(256) void scan2_kernel(int* __restrict__ bsum, int nb) {
  __shared__ int s[256];
  int t = threadIdx.x;
  int v = (t < nb) ? bsum[t] : 0;
  s[t] = v;
  __syncthreads();
  #pragma unroll
  for (int off = 1; off < 256; off <<= 1) {
    int tv = (t >= off) ? s[t - off] : 0;
    __syncthreads();
    s[t] += tv;
    __syncthreads();
  }
  if (t < nb) bsum[t] = s[t] - v;  // exclusive
}

__global__ __launch_bounds__(256) void scan3_kernel(
    const int* __restrict__ excl, const int* __restrict__ bsum,
    int* __restrict__ start, int* __restrict__ cur, int n) {
  int i = blockIdx.x * 256 + threadIdx.x;
  if (i < n) {
    int v = excl[i] + bsum[blockIdx.x];
    start[i] = v;
    cur[i] = v;
  }
}

__global__ __launch_bounds__(256) void scatter_kernel(
    const int* __restrict__ edge_src, int* __restrict__ cur,
    int* __restrict__ els, int E) {
  int e = blockIdx.x * 256 + threadIdx.x;
  if (e < E) {
    int pos = atomicAdd(&cur[edge_src[e]], 1);
    els[pos] = e;
  }
}

// ---------------- weight prep (bf16 MFMA fragments) ----------------
__global__ __launch_bounds__(256) void prep_kernel(
    const float* __restrict__ W2, const float* __restrict__ W1,
    const float* __restrict__ b2, unsigned short* __restrict__ W2p,
    unsigned short* __restrict__ W1p, float* __restrict__ b2p)
{
  int gid = blockIdx.x * 256 + threadIdx.x;
  const int NW2 = NT_TOT * 3 * 64;
  const int NW1 = 18 * 64;
  if (gid < NW2) {
    int tile = gid >> 6, ln = gid & 63;
    int nt = tile / 3, s = tile - nt * 3;
    int J = nt * 16 + (ln & 15);
    int jo = perm_col(J);
    int kbase = s * 32 + ((ln >> 4) << 3);
    #pragma unroll
    for (int j = 0; j < 8; ++j)
      W2p[(size_t)gid * 8 + j] = f2bf(W2[(kbase + j) * WNUM + jo]);
  } else if (gid < NW2 + NW1) {
    int g = gid - NW2;
    int tile = g >> 6, ln = g & 63;
    int nt = tile / 3, s = tile - nt * 3;
    int col = nt * 16 + (ln & 15);
    int kbase = s * 32 + ((ln >> 4) << 3);
    #pragma unroll
    for (int j = 0; j < 8; ++j)
      W1p[(size_t)g * 8 + j] = f2bf(W1[(kbase + j) * HID + col]);
  } else if (gid < NW2 + NW1 + WNUM) {
    int J = gid - (NW2 + NW1);
    b2p[J] = b2[perm_col(J)];
  }
}

// K1: h = relu(edge_attr @ W1 + b1) in bf16 via MFMA. 64 edges/block, 4 waves.
__global__ __launch_bounds__(256) void gemm1_mfma(
    const float* __restrict__ A, const unsigned short* __restrict__ W1p,
    const float* __restrict__ b1, unsigned short* __restrict__ h)
{
  const int tid = threadIdx.x, ln = tid & 63, wv = tid >> 6;
  const int e0 = blockIdx.x * 64;
  const int row = e0 + wv * 16 + (ln & 15);
  short8 af[3];
  #pragma unroll
  for (int s = 0; s < 3; ++s) {
    const float* p = A + (size_t)row * HID + s * 32 + ((ln >> 4) << 3);
    short8 v;
    #pragma unroll
    for (int j = 0; j < 8; ++j) v[j] = (short)f2bf(p[j]);
    af[s] = v;
  }
  #pragma unroll
  for (int nt = 0; nt < 6; ++nt) {
    f32x4 acc = {0.f, 0.f, 0.f, 0.f};
    #pragma unroll
    for (int s = 0; s < 3; ++s) {
      short8 bfr = *(const short8*)(W1p + ((size_t)(nt * 3 + s) * 64 + ln) * 8);
      acc = __builtin_amdgcn_mfma_f32_16x16x32_bf16(af[s], bfr, acc, 0, 0, 0);
    }
    int col = nt * 16 + (ln & 15);
    float bb = b1[col];
    #pragma unroll
    for (int r = 0; r < 4; ++r) {
      float v = fmaxf(acc[r] + bb, 0.f);
      int er = e0 + wv * 16 + ((ln >> 4) << 2) + r;
      h[(size_t)er * HID + col] = f2bf(v);
    }
  }
}

// K2: fused  w = h@W2+b2 (MFMA, f32 LDS, wave-pipelined) -> TP -> direct store
__global__ __launch_bounds__(512, 4) void fused_mfma(
    const unsigned short* __restrict__ h, const unsigned short* __restrict__ W2p,
    const float* __restrict__ b2p, const float* __restrict__ node_attr,
    const float* __restrict__ edge_sh, const int* __restrict__ edge_dst,
    float* __restrict__ tpg)
{
  __shared__ __align__(16) float ws[EPB][212];  // w chunk, f32, single buffer (54.3 KB)
  __shared__ float x0s[EPB][32];
  __shared__ float x1s[EPB][3][8];
  __shared__ float crs[EPB][3][8];
  __shared__ float dsu[EPB][8];
  __shared__ float sh1s[EPB][3];
  __shared__ float s0s[EPB];
  __shared__ int   dsts[EPB];

  const int tid = threadIdx.x;
  const int e0 = blockIdx.x * EPB;

  if (tid < EPB) {
    dsts[tid] = edge_dst[e0 + tid];
    s0s[tid] = edge_sh[(size_t)(e0 + tid) * 4];
  }
  if (tid >= 128 && tid < 128 + EPB * 3) {
    int i = tid - 128, e = i / 3, m = i - e * 3;
    sh1s[e][m] = edge_sh[(size_t)(e0 + e) * 4 + 1 + m];
  }
  __syncthreads();

  for (int idx = tid; idx < EPB * NA_DIM; idx += 512) {
    int e = idx / NA_DIM, c = idx - e * NA_DIM;
    float v = node_attr[(size_t)dsts[e] * NA_DIM + c];
    if (c < 32) x0s[e][c] = v;
    else { int q = c - 32; x1s[e][q % 3][q / 3] = v; }
  }
  __syncthreads();

  { // per-(e,u) derived quantities; 512 = 64*8 exact
    int e = tid >> 3, u = tid & 7;
    float a0 = x1s[e][0][u], a1 = x1s[e][1][u], a2 = x1s[e][2][u];
    float b0 = sh1s[e][0], b1v = sh1s[e][1], b2v = sh1s[e][2];
    dsu[e][u] = a0 * b0 + a1 * b1v + a2 * b2v;
    crs[e][0][u] = a1 * b2v - a2 * b1v;
    crs[e][1][u] = a2 * b0 - a0 * b2v;
    crs[e][2][u] = a0 * b1v - a1 * b0;
  }

  const int ln = tid & 63, wv = tid >> 6;
  const int c16 = ln & 15, q4 = (ln >> 4) << 2;
  short8 af[4][3];
  #pragma unroll
  for (int mt = 0; mt < 4; ++mt)
    #pragma unroll
    for (int s = 0; s < 3; ++s)
      af[mt][s] = *(const short8*)(h + (size_t)(e0 + mt * 16 + c16) * HID
                                     + s * 32 + ((ln >> 4) << 3));

  // wave tiles: tile0 = wv (always, l<128); tile1 = wv+8 (waves 0..4, l>=128)
  const bool has1 = wv < (NTC - 8);
  const int l0 = wv * 16 + c16;
  const int pc0 = (l0 & 96) | ((l0 + ((l0 >> 5) << 2)) & 31);  // w1-region swizzle
  f32x4 acc0[4], acc1[4];
  float bias0 = 0.f, bias1 = 0.f;

  auto issue = [&](int cc) {  // MFMA into regs + bias prefetch; no LDS access
    bias0 = b2p[cc * CHW + l0];
    int nt = cc * NTC + wv;
    #pragma unroll
    for (int mt = 0; mt < 4; ++mt) acc0[mt] = (f32x4){0.f, 0.f, 0.f, 0.f};
    #pragma unroll
    for (int s = 0; s < 3; ++s) {
      short8 bfr = *(const short8*)(W2p + ((size_t)(nt * 3 + s) * 64 + ln) * 8);
      #pragma unroll
      for (int mt = 0; mt < 4; ++mt)
        acc0[mt] = __builtin_amdgcn_mfma_f32_16x16x32_bf16(af[mt][s], bfr, acc0[mt], 0, 0, 0);
    }
    if (has1) {
      bias1 = b2p[cc * CHW + l0 + 128];
      int nt1 = cc * NTC + wv + 8;
      #pragma unroll
      for (int mt = 0; mt < 4; ++mt) acc1[mt] = (f32x4){0.f, 0.f, 0.f, 0.f};
      #pragma unroll
      for (int s = 0; s < 3; ++s) {
        short8 bfr = *(const short8*)(W2p + ((size_t)(nt1 * 3 + s) * 64 + ln) * 8);
        #pragma unroll
        for (int mt = 0; mt < 4; ++mt)
          acc1[mt] = __builtin_amdgcn_mfma_f32_16x16x32_bf16(af[mt][s], bfr, acc1[mt], 0, 0, 0);
      }
    }
  };
  auto epilogue = [&]() {  // regs -> ws (f32, no converts)
    #pragma unroll
    for (int mt = 0; mt < 4; ++mt)
      #pragma unroll
      for (int r = 0; r < 4; ++r)
        ws[mt * 16 + q4 + r][pc0] = acc0[mt][r] + bias0;
    if (has1) {
      #pragma unroll
      for (int mt = 0; mt < 4; ++mt)
        #pragma unroll
        for (int r = 0; r < 4; ++r)
          ws[mt * 16 + q4 + r][l0 + 128] = acc1[mt][r] + bias1;
    }
  };

  issue(0);
  epilogue();
  __syncthreads();

  const int e = tid >> 3, tt = tid & 7;
  const float s0 = s0s[e];
  float* tpr = tpg + (size_t)(e0 + e) * OUT_DIM;

  for (int ch = 0; ch < NCH; ++ch) {
    if (ch + 1 < NCH) issue(ch + 1);      // matrix pipe busy under TP below
    __builtin_amdgcn_sched_barrier(0);    // keep MFMA issue ahead of TP

    if (tt < 4) {
      f32x4 a4 = {0.f, 0.f, 0.f, 0.f};
      #pragma unroll
      for (int u0 = 0; u0 < 32; u0 += 4) {
        int pu = (u0 + (tt << 2)) & 31;   // swizzled LDS col of logical u0
        f32x4 wq = *(const f32x4*)&ws[e][(tt << 5) + pu];
        f32x4 xq = *(const f32x4*)&x0s[e][u0];
        a4 += wq * xq;
      }
      f32x4 d4 = {0.f, 0.f, 0.f, 0.f};
      #pragma unroll
      for (int u0 = 0; u0 < 8; u0 += 4) {
        f32x4 wq = *(const f32x4*)&ws[e][168 + (tt << 3) + u0];
        f32x4 dq = *(const f32x4*)&dsu[e][u0];
        d4 += wq * dq;
      }
      float sum1 = (a4[0] + a4[1]) + (a4[2] + a4[3]);
      float sum2 = (d4[0] + d4[1]) + (d4[2] + d4[3]);
      tpr[4 * ch + tt] = N0f * (s0 * sum1 + INV_S3 * sum2);
    } else if (tt < 7) {
      const int m = tt - 4;
      f32x4 a4 = {0.f, 0.f, 0.f, 0.f};
      #pragma unroll
      for (int u0 = 0; u0 < 32; u0 += 4) {
        f32x4 wq = *(const f32x4*)&ws[e][128 + u0];
        f32x4 xq = *(const f32x4*)&x0s[e][u0];
        a4 += wq * xq;
      }
      f32x4 b4 = {0.f, 0.f, 0.f, 0.f};
      #pragma unroll
      for (int u0 = 0; u0 < 8; u0 += 4) {
        f32x4 wq = *(const f32x4*)&ws[e][160 + u0];
        f32x4 xq = *(const f32x4*)&x1s[e][m][u0];
        b4 += wq * xq;
      }
      float sum1 = (a4[0] + a4[1]) + (a4[2] + a4[3]);
      float sum2 = (b4[0] + b4[1]) + (b4[2] + b4[3]);
      tpr[32 + ch * 3 + m] = N0f * (sh1s[e][m] * sum1 + s0 * sum2);
    } else {
      #pragma unroll
      for (int m = 0; m < 3; ++m) {
        f32x4 c4 = {0.f, 0.f, 0.f, 0.f};
        #pragma unroll
        for (int u0 = 0; u0 < 8; u0 += 4) {
          f32x4 wq = *(const f32x4*)&ws[e][200 + u0];
          f32x4 cq = *(const f32x4*)&crs[e][m][u0];
          c4 += wq * cq;
        }
        tpr[56 + ch * 3 + m] = C_OUT1E * ((c4[0] + c4[1]) + (c4[2] + c4[3]));
      }
    }

    __syncthreads();                     // TP reads of ws complete
    if (ch + 1 < NCH) epilogue();        // write next chunk into ws
    __syncthreads();                     // ws ready for next TP
  }
}

// K3: per-node mean over sorted edge lists (no atomics)
__global__ __launch_bounds__(256) void gather_kernel(
    const float* __restrict__ tp, const int* __restrict__ els,
    const int* __restrict__ start, const int* __restrict__ hist,
    float* __restrict__ out, int total)
{
  int idx = blockIdx.x * 256 + threadIdx.x;
  if (idx >= total) return;
  int node = idx / OUT_DIM, o = idx - node * OUT_DIM;
  int s = start[node], c = hist[node];
  float sum = 0.f;
  for (int i = 0; i < c; ++i)
    sum += tp[(size_t)els[s + i] * OUT_DIM + o];
  out[idx] = sum / (float)(c > 0 ? c : 1);
}

extern "C" void kernel_launch(void* const* d_in, const int* in_sizes, int n_in,
                              void* d_out, int out_size, void* d_ws, size_t ws_size,
                              hipStream_t stream) {
  const float* node_attr = (const float*)d_in[0];
  const float* edge_attr = (const float*)d_in[1];
  const float* edge_sh   = (const float*)d_in[2];
  const float* W1        = (const float*)d_in[3];
  const float* b1        = (const float*)d_in[4];
  const float* W2        = (const float*)d_in[5];
  const float* b2        = (const float*)d_in[6];
  const int*   edge_src  = (const int*)d_in[7];
  const int*   edge_dst  = (const int*)d_in[8];
  float* out = (float*)d_out;

  const int E = in_sizes[7];
  const int N = in_sizes[0] / NA_DIM;

  char* wsb = (char*)d_ws;
  int*   hist  = (int*)(wsb + 0x000000);          // 40000 ints
  int*   excl  = (int*)(wsb + 0x040000);
  int*   start = (int*)(wsb + 0x080000);
  int*   cur   = (int*)(wsb + 0x0C0000);
  int*   bsum  = (int*)(wsb + 0x100000);          // 256 ints
  int*   els   = (int*)(wsb + 0x110000);          // 120000 ints
  unsigned short* W2p = (unsigned short*)(wsb + 0x200000);   // 320 KB
  unsigned short* W1p = (unsigned short*)(wsb + 0x280000);
  float*          b2p = (float*)(wsb + 0x2C0000);
  unsigned short* hbf = (unsigned short*)(wsb + 0x300000);   // 23 MB
  float*          tpg = (float*)(wsb + 0x1C00000);           // 38.4 MB

  const int NB = (N + 255) / 256;  // 157

  zero_int_kernel<<<NB, 256, 0, stream>>>(hist, N);
  hist_kernel<<<(E + 255) / 256, 256, 0, stream>>>(edge_src, hist, E);
  scan1_kernel<<<NB, 256, 0, stream>>>(hist, excl, bsum, N);
  scan2_kernel<<<1, 256, 0, stream>>>(bsum, NB);
  scan3_kernel<<<NB, 256, 0, stream>>>(excl, bsum, start, cur, N);
  scatter_kernel<<<(E + 255) / 256, 256, 0, stream>>>(edge_src, cur, els, E);

  const int prep_total = NT_TOT * 3 * 64 + 18 * 64 + WNUM;
  prep_kernel<<<(prep_total + 255) / 256, 256, 0, stream>>>(W2, W1, b2, W2p, W1p, b2p);

  gemm1_mfma<<<E / 64, 256, 0, stream>>>(edge_attr, W1p, b1, hbf);
  fused_mfma<<<E / EPB, 512, 0, stream>>>(hbf, W2p, b2p, node_attr, edge_sh,
                                          edge_dst, tpg);
  gather_kernel<<<(N * OUT_DIM + 255) / 256, 256, 0, stream>>>(
      tpg, els, start, hist, out, N * OUT_DIM);
}

// Round 8
// 232.955 us; speedup vs baseline: 2.4562x; 2.4562x over previous
//
#include <hip/hip_runtime.h>

typedef short short8 __attribute__((ext_vector_type(8)));
typedef float f32x4 __attribute__((ext_vector_type(4)));

#define HID 96
#define WNUM 1664
#define NA_DIM 56
#define OUT_DIM 80
#define EPB 64
#define NT_TOT 104   // 1664/16
#define CHW 208      // cols per chunk
#define NCH 8
#define NTC 13       // n-tiles per chunk

#define N0f 0.158113883f      // 1/sqrt(40)
#define INV_S3 0.5773502692f  // 1/sqrt(3)
#define C_OUT1E 0.25f         // (1/sqrt(2))*(1/sqrt(8))

__device__ __forceinline__ unsigned short f2bf(float x) {
  unsigned u = __builtin_bit_cast(unsigned, x);
  u += 0x7FFFu + ((u >> 16) & 1u);
  return (unsigned short)(u >> 16);
}

// column permutation: new col J -> original W2 col
__device__ __forceinline__ int perm_col(int J) {
  int c = J / CHW, l = J - (J / CHW) * CHW;
  if (l < 128) { int vp = l >> 5, u = l & 31; return u * 32 + 4 * c + vp; }          // w1
  if (l < 160) { int u = l - 128; return 1024 + u * 8 + c; }                          // w2
  if (l < 168) { int u = l - 160; return 1280 + u * 8 + c; }                          // w3
  if (l < 200) { int q = l - 168; int vp = q >> 3, u = q & 7; return 1344 + u * 32 + 4 * c + vp; } // w4
  { int u = l - 200; return 1600 + u * 8 + c; }                                       // w5
}

__global__ __launch_bounds__(256) void zero_int_kernel(int* __restrict__ p, int n) {
  int i = blockIdx.x * 256 + threadIdx.x;
  if (i < n) p[i] = 0;
}

// ---------------- counting sort of edges by edge_src ----------------
__global__ __launch_bounds__(256) void hist_kernel(
    const int* __restrict__ edge_src, int* __restrict__ hist, int E) {
  int e = blockIdx.x * 256 + threadIdx.x;
  if (e < E) atomicAdd(&hist[edge_src[e]], 1);
}

__global__ __launch_bounds__(256) void scan1_kernel(
    const int* __restrict__ hist, int* __restrict__ excl,
    int* __restrict__ bsum, int n) {
  __shared__ int s[256];
  int t = threadIdx.x, i = blockIdx.x * 256 + t;
  int v = (i < n) ? hist[i] : 0;
  s[t] = v;
  __syncthreads();
  #pragma unroll
  for (int off = 1; off < 256; off <<= 1) {
    int tv = (t >= off) ? s[t - off] : 0;
    __syncthreads();
    s[t] += tv;
    __syncthreads();
  }
  if (i < n) excl[i] = s[t] - v;
  if (t == 255) bsum[blockIdx.x] = s[255];
}

__global__ __launch_bounds__(256) void scan2_kernel(int* __restrict__ bsum, int nb) {
  __shared__ int s[256];
  int t = threadIdx.x;
  int v = (t < nb) ? bsum[t] : 0;
  s[t] = v;
  __syncthreads();
  #pragma unroll
  for (int off = 1; off < 256; off <<= 1) {
    int tv = (t >= off) ? s[t - off] : 0;
    __syncthreads();
    s[t] += tv;
    __syncthreads();
  }
  if (t < nb) bsum[t] = s[t] - v;  // exclusive
}

__global__ __launch_bounds__(256) void scan3_kernel(
    const int* __restrict__ excl, const int* __restrict__ bsum,
    int* __restrict__ start, int* __restrict__ cur, int n) {
  int i = blockIdx.x * 256 + threadIdx.x;
  if (i < n) {
    int v = excl[i] + bsum[blockIdx.x];
    start[i] = v;
    cur[i] = v;
  }
}

__global__ __launch_bounds__(256) void scatter_kernel(
    const int* __restrict__ edge_src, int* __restrict__ cur,
    int* __restrict__ els, int E) {
  int e = blockIdx.x * 256 + threadIdx.x;
  if (e < E) {
    int pos = atomicAdd(&cur[edge_src[e]], 1);
    els[pos] = e;
  }
}

// ---------------- weight prep (bf16 MFMA fragments) ----------------
__global__ __launch_bounds__(256) void prep_kernel(
    const float* __restrict__ W2, const float* __restrict__ W1,
    const float* __restrict__ b2, unsigned short* __restrict__ W2p,
    unsigned short* __restrict__ W1p, float* __restrict__ b2p)
{
  int gid = blockIdx.x * 256 + threadIdx.x;
  const int NW2 = NT_TOT * 3 * 64;
  const int NW1 = 18 * 64;
  if (gid < NW2) {
    int tile = gid >> 6, ln = gid & 63;
    int nt = tile / 3, s = tile - nt * 3;
    int J = nt * 16 + (ln & 15);
    int jo = perm_col(J);
    int kbase = s * 32 + ((ln >> 4) << 3);
    #pragma unroll
    for (int j = 0; j < 8; ++j)
      W2p[(size_t)gid * 8 + j] = f2bf(W2[(kbase + j) * WNUM + jo]);
  } else if (gid < NW2 + NW1) {
    int g = gid - NW2;
    int tile = g >> 6, ln = g & 63;
    int nt = tile / 3, s = tile - nt * 3;
    int col = nt * 16 + (ln & 15);
    int kbase = s * 32 + ((ln >> 4) << 3);
    #pragma unroll
    for (int j = 0; j < 8; ++j)
      W1p[(size_t)g * 8 + j] = f2bf(W1[(kbase + j) * HID + col]);
  } else if (gid < NW2 + NW1 + WNUM) {
    int J = gid - (NW2 + NW1);
    b2p[J] = b2[perm_col(J)];
  }
}

// K1: h = relu(edge_attr @ W1 + b1) in bf16 via MFMA. 64 edges/block, 4 waves.
__global__ __launch_bounds__(256) void gemm1_mfma(
    const float* __restrict__ A, const unsigned short* __restrict__ W1p,
    const float* __restrict__ b1, unsigned short* __restrict__ h)
{
  const int tid = threadIdx.x, ln = tid & 63, wv = tid >> 6;
  const int e0 = blockIdx.x * 64;
  const int row = e0 + wv * 16 + (ln & 15);
  short8 af[3];
  #pragma unroll
  for (int s = 0; s < 3; ++s) {
    const float* p = A + (size_t)row * HID + s * 32 + ((ln >> 4) << 3);
    short8 v;
    #pragma unroll
    for (int j = 0; j < 8; ++j) v[j] = (short)f2bf(p[j]);
    af[s] = v;
  }
  #pragma unroll
  for (int nt = 0; nt < 6; ++nt) {
    f32x4 acc = {0.f, 0.f, 0.f, 0.f};
    #pragma unroll
    for (int s = 0; s < 3; ++s) {
      short8 bfr = *(const short8*)(W1p + ((size_t)(nt * 3 + s) * 64 + ln) * 8);
      acc = __builtin_amdgcn_mfma_f32_16x16x32_bf16(af[s], bfr, acc, 0, 0, 0);
    }
    int col = nt * 16 + (ln & 15);
    float bb = b1[col];
    #pragma unroll
    for (int r = 0; r < 4; ++r) {
      float v = fmaxf(acc[r] + bb, 0.f);
      int er = e0 + wv * 16 + ((ln >> 4) << 2) + r;
      h[(size_t)er * HID + col] = f2bf(v);
    }
  }
}

// K2: fused  w = h@W2+b2 (MFMA, f32 LDS, wave-pipelined) -> TP -> direct store
__global__ __launch_bounds__(512, 2) void fused_mfma(
    const unsigned short* __restrict__ h, const unsigned short* __restrict__ W2p,
    const float* __restrict__ b2p, const float* __restrict__ node_attr,
    const float* __restrict__ edge_sh, const int* __restrict__ edge_dst,
    float* __restrict__ tpg)
{
  __shared__ __align__(16) float ws[EPB][212];  // w chunk, f32, single buffer (54.3 KB)
  __shared__ float x0s[EPB][32];
  __shared__ float x1s[EPB][3][8];
  __shared__ float crs[EPB][3][8];
  __shared__ float dsu[EPB][8];
  __shared__ float sh1s[EPB][3];
  __shared__ float s0s[EPB];
  __shared__ int   dsts[EPB];

  const int tid = threadIdx.x;
  const int e0 = blockIdx.x * EPB;

  if (tid < EPB) {
    dsts[tid] = edge_dst[e0 + tid];
    s0s[tid] = edge_sh[(size_t)(e0 + tid) * 4];
  }
  if (tid >= 128 && tid < 128 + EPB * 3) {
    int i = tid - 128, e = i / 3, m = i - e * 3;
    sh1s[e][m] = edge_sh[(size_t)(e0 + e) * 4 + 1 + m];
  }
  __syncthreads();

  for (int idx = tid; idx < EPB * NA_DIM; idx += 512) {
    int e = idx / NA_DIM, c = idx - e * NA_DIM;
    float v = node_attr[(size_t)dsts[e] * NA_DIM + c];
    if (c < 32) x0s[e][c] = v;
    else { int q = c - 32; x1s[e][q % 3][q / 3] = v; }
  }
  __syncthreads();

  { // per-(e,u) derived quantities; 512 = 64*8 exact
    int e = tid >> 3, u = tid & 7;
    float a0 = x1s[e][0][u], a1 = x1s[e][1][u], a2 = x1s[e][2][u];
    float b0 = sh1s[e][0], b1v = sh1s[e][1], b2v = sh1s[e][2];
    dsu[e][u] = a0 * b0 + a1 * b1v + a2 * b2v;
    crs[e][0][u] = a1 * b2v - a2 * b1v;
    crs[e][1][u] = a2 * b0 - a0 * b2v;
    crs[e][2][u] = a0 * b1v - a1 * b0;
  }

  const int ln = tid & 63, wv = tid >> 6;
  const int c16 = ln & 15, q4 = (ln >> 4) << 2;
  short8 af[4][3];
  #pragma unroll
  for (int mt = 0; mt < 4; ++mt)
    #pragma unroll
    for (int s = 0; s < 3; ++s)
      af[mt][s] = *(const short8*)(h + (size_t)(e0 + mt * 16 + c16) * HID
                                     + s * 32 + ((ln >> 4) << 3));

  // wave tiles: tile0 = wv (always, l<128); tile1 = wv+8 (waves 0..4, l>=128)
  const bool has1 = wv < (NTC - 8);
  const int l0 = wv * 16 + c16;
  const int pc0 = (l0 & 96) | ((l0 + ((l0 >> 5) << 2)) & 31);  // w1-region swizzle
  f32x4 acc0[4], acc1[4];
  float bias0 = 0.f, bias1 = 0.f;

  auto issue = [&](int cc) {  // MFMA into regs + bias prefetch; no LDS access
    bias0 = b2p[cc * CHW + l0];
    int nt = cc * NTC + wv;
    #pragma unroll
    for (int mt = 0; mt < 4; ++mt) acc0[mt] = (f32x4){0.f, 0.f, 0.f, 0.f};
    #pragma unroll
    for (int s = 0; s < 3; ++s) {
      short8 bfr = *(const short8*)(W2p + ((size_t)(nt * 3 + s) * 64 + ln) * 8);
      #pragma unroll
      for (int mt = 0; mt < 4; ++mt)
        acc0[mt] = __builtin_amdgcn_mfma_f32_16x16x32_bf16(af[mt][s], bfr, acc0[mt], 0, 0, 0);
    }
    if (has1) {
      bias1 = b2p[cc * CHW + l0 + 128];
      int nt1 = cc * NTC + wv + 8;
      #pragma unroll
      for (int mt = 0; mt < 4; ++mt) acc1[mt] = (f32x4){0.f, 0.f, 0.f, 0.f};
      #pragma unroll
      for (int s = 0; s < 3; ++s) {
        short8 bfr = *(const short8*)(W2p + ((size_t)(nt1 * 3 + s) * 64 + ln) * 8);
        #pragma unroll
        for (int mt = 0; mt < 4; ++mt)
          acc1[mt] = __builtin_amdgcn_mfma_f32_16x16x32_bf16(af[mt][s], bfr, acc1[mt], 0, 0, 0);
      }
    }
  };
  auto epilogue = [&]() {  // regs -> ws (f32, no converts)
    #pragma unroll
    for (int mt = 0; mt < 4; ++mt)
      #pragma unroll
      for (int r = 0; r < 4; ++r)
        ws[mt * 16 + q4 + r][pc0] = acc0[mt][r] + bias0;
    if (has1) {
      #pragma unroll
      for (int mt = 0; mt < 4; ++mt)
        #pragma unroll
        for (int r = 0; r < 4; ++r)
          ws[mt * 16 + q4 + r][l0 + 128] = acc1[mt][r] + bias1;
    }
  };

  issue(0);
  epilogue();
  __syncthreads();

  const int e = tid >> 3, tt = tid & 7;
  const float s0 = s0s[e];
  float* tpr = tpg + (size_t)(e0 + e) * OUT_DIM;

  for (int ch = 0; ch < NCH; ++ch) {
    if (ch + 1 < NCH) issue(ch + 1);      // matrix pipe busy under TP below
    __builtin_amdgcn_sched_barrier(0);    // keep MFMA issue ahead of TP

    if (tt < 4) {
      f32x4 a4 = {0.f, 0.f, 0.f, 0.f};
      #pragma unroll
      for (int u0 = 0; u0 < 32; u0 += 4) {
        int pu = (u0 + (tt << 2)) & 31;   // swizzled LDS col of logical u0
        f32x4 wq = *(const f32x4*)&ws[e][(tt << 5) + pu];
        f32x4 xq = *(const f32x4*)&x0s[e][u0];
        a4 += wq * xq;
      }
      f32x4 d4 = {0.f, 0.f, 0.f, 0.f};
      #pragma unroll
      for (int u0 = 0; u0 < 8; u0 += 4) {
        f32x4 wq = *(const f32x4*)&ws[e][168 + (tt << 3) + u0];
        f32x4 dq = *(const f32x4*)&dsu[e][u0];
        d4 += wq * dq;
      }
      float sum1 = (a4[0] + a4[1]) + (a4[2] + a4[3]);
      float sum2 = (d4[0] + d4[1]) + (d4[2] + d4[3]);
      tpr[4 * ch + tt] = N0f * (s0 * sum1 + INV_S3 * sum2);
    } else if (tt < 7) {
      const int m = tt - 4;
      f32x4 a4 = {0.f, 0.f, 0.f, 0.f};
      #pragma unroll
      for (int u0 = 0; u0 < 32; u0 += 4) {
        f32x4 wq = *(const f32x4*)&ws[e][128 + u0];
        f32x4 xq = *(const f32x4*)&x0s[e][u0];
        a4 += wq * xq;
      }
      f32x4 b4 = {0.f, 0.f, 0.f, 0.f};
      #pragma unroll
      for (int u0 = 0; u0 < 8; u0 += 4) {
        f32x4 wq = *(const f32x4*)&ws[e][160 + u0];
        f32x4 xq = *(const f32x4*)&x1s[e][m][u0];
        b4 += wq * xq;
      }
      float sum1 = (a4[0] + a4[1]) + (a4[2] + a4[3]);
      float sum2 = (b4[0] + b4[1]) + (b4[2] + b4[3]);
      tpr[32 + ch * 3 + m] = N0f * (sh1s[e][m] * sum1 + s0 * sum2);
    } else {
      #pragma unroll
      for (int m = 0; m < 3; ++m) {
        f32x4 c4 = {0.f, 0.f, 0.f, 0.f};
        #pragma unroll
        for (int u0 = 0; u0 < 8; u0 += 4) {
          f32x4 wq = *(const f32x4*)&ws[e][200 + u0];
          f32x4 cq = *(const f32x4*)&crs[e][m][u0];
          c4 += wq * cq;
        }
        tpr[56 + ch * 3 + m] = C_OUT1E * ((c4[0] + c4[1]) + (c4[2] + c4[3]));
      }
    }

    __syncthreads();                     // TP reads of ws complete
    if (ch + 1 < NCH) epilogue();        // write next chunk into ws
    __syncthreads();                     // ws ready for next TP
  }
}

// K3: per-node mean over sorted edge lists (no atomics)
__global__ __launch_bounds__(256) void gather_kernel(
    const float* __restrict__ tp, const int* __restrict__ els,
    const int* __restrict__ start, const int* __restrict__ hist,
    float* __restrict__ out, int total)
{
  int idx = blockIdx.x * 256 + threadIdx.x;
  if (idx >= total) return;
  int node = idx / OUT_DIM, o = idx - node * OUT_DIM;
  int s = start[node], c = hist[node];
  float sum = 0.f;
  for (int i = 0; i < c; ++i)
    sum += tp[(size_t)els[s + i] * OUT_DIM + o];
  out[idx] = sum / (float)(c > 0 ? c : 1);
}

extern "C" void kernel_launch(void* const* d_in, const int* in_sizes, int n_in,
                              void* d_out, int out_size, void* d_ws, size_t ws_size,
                              hipStream_t stream) {
  const float* node_attr = (const float*)d_in[0];
  const float* edge_attr = (const float*)d_in[1];
  const float* edge_sh   = (const float*)d_in[2];
  const float* W1        = (const float*)d_in[3];
  const float* b1        = (const float*)d_in[4];
  const float* W2        = (const float*)d_in[5];
  const float* b2        = (const float*)d_in[6];
  const int*   edge_src  = (const int*)d_in[7];
  const int*   edge_dst  = (const int*)d_in[8];
  float* out = (float*)d_out;

  const int E = in_sizes[7];
  const int N = in_sizes[0] / NA_DIM;

  char* wsb = (char*)d_ws;
  int*   hist  = (int*)(wsb + 0x000000);          // 40000 ints
  int*   excl  = (int*)(wsb + 0x040000);
  int*   start = (int*)(wsb + 0x080000);
  int*   cur   = (int*)(wsb + 0x0C0000);
  int*   bsum  = (int*)(wsb + 0x100000);          // 256 ints
  int*   els   = (int*)(wsb + 0x110000);          // 120000 ints
  unsigned short* W2p = (unsigned short*)(wsb + 0x200000);   // 320 KB
  unsigned short* W1p = (unsigned short*)(wsb + 0x280000);
  float*          b2p = (float*)(wsb + 0x2C0000);
  unsigned short* hbf = (unsigned short*)(wsb + 0x300000);   // 23 MB
  float*          tpg = (float*)(wsb + 0x1C00000);           // 38.4 MB

  const int NB = (N + 255) / 256;  // 157

  zero_int_kernel<<<NB, 256, 0, stream>>>(hist, N);
  hist_kernel<<<(E + 255) / 256, 256, 0, stream>>>(edge_src, hist, E);
  scan1_kernel<<<NB, 256, 0, stream>>>(hist, excl, bsum, N);
  scan2_kernel<<<1, 256, 0, stream>>>(bsum, NB);
  scan3_kernel<<<NB, 256, 0, stream>>>(excl, bsum, start, cur, N);
  scatter_kernel<<<(E + 255) / 256, 256, 0, stream>>>(edge_src, cur, els, E);

  const int prep_total = NT_TOT * 3 * 64 + 18 * 64 + WNUM;
  prep_kernel<<<(prep_total + 255) / 256, 256, 0, stream>>>(W2, W1, b2, W2p, W1p, b2p);

  gemm1_mfma<<<E / 64, 256, 0, stream>>>(edge_attr, W1p, b1, hbf);
  fused_mfma<<<E / EPB, 512, 0, stream>>>(hbf, W2p, b2p, node_attr, edge_sh,
                                          edge_dst, tpg);
  gather_kernel<<<(N * OUT_DIM + 255) / 256, 256, 0, stream>>>(
      tpg, els, start, hist, out, N * OUT_DIM);
}

// Round 9
// 213.034 us; speedup vs baseline: 2.6858x; 1.0935x over previous
//
#include <hip/hip_runtime.h>

typedef short short8 __attribute__((ext_vector_type(8)));
typedef float f32x4 __attribute__((ext_vector_type(4)));

#define HID 96
#define WNUM 1664
#define NA_DIM 56
#define OUT_DIM 80
#define EPB 64
#define NT_TOT 104   // 1664/16
#define CHW 208      // cols per chunk
#define NCH 8
#define NTC 13       // n-tiles per chunk

#define N0f 0.158113883f      // 1/sqrt(40)
#define INV_S3 0.5773502692f  // 1/sqrt(3)
#define C_OUT1E 0.25f         // (1/sqrt(2))*(1/sqrt(8))

__device__ __forceinline__ unsigned short f2bf(float x) {
  unsigned u = __builtin_bit_cast(unsigned, x);
  u += 0x7FFFu + ((u >> 16) & 1u);
  return (unsigned short)(u >> 16);
}

// column permutation: new col J -> original W2 col
__device__ __forceinline__ int perm_col(int J) {
  int c = J / CHW, l = J - (J / CHW) * CHW;
  if (l < 128) { int vp = l >> 5, u = l & 31; return u * 32 + 4 * c + vp; }          // w1
  if (l < 160) { int u = l - 128; return 1024 + u * 8 + c; }                          // w2
  if (l < 168) { int u = l - 160; return 1280 + u * 8 + c; }                          // w3
  if (l < 200) { int q = l - 168; int vp = q >> 3, u = q & 7; return 1344 + u * 32 + 4 * c + vp; } // w4
  { int u = l - 200; return 1600 + u * 8 + c; }                                       // w5
}

__global__ __launch_bounds__(256) void zero_int_kernel(int* __restrict__ p, int n) {
  int i = blockIdx.x * 256 + threadIdx.x;
  if (i < n) p[i] = 0;
}

// ---------------- counting sort of edges by edge_src ----------------
__global__ __launch_bounds__(256) void hist_kernel(
    const int* __restrict__ edge_src, int* __restrict__ hist, int E) {
  int e = blockIdx.x * 256 + threadIdx.x;
  if (e < E) atomicAdd(&hist[edge_src[e]], 1);
}

__global__ __launch_bounds__(256) void scan1_kernel(
    const int* __restrict__ hist, int* __restrict__ excl,
    int* __restrict__ bsum, int n) {
  __shared__ int s[256];
  int t = threadIdx.x, i = blockIdx.x * 256 + t;
  int v = (i < n) ? hist[i] : 0;
  s[t] = v;
  __syncthreads();
  #pragma unroll
  for (int off = 1; off < 256; off <<= 1) {
    int tv = (t >= off) ? s[t - off] : 0;
    __syncthreads();
    s[t] += tv;
    __syncthreads();
  }
  if (i < n) excl[i] = s[t] - v;
  if (t == 255) bsum[blockIdx.x] = s[255];
}

__global__ __launch_bounds__(256) void scan2_kernel(int* __restrict__ bsum, int nb) {
  __shared__ int s[256];
  int t = threadIdx.x;
  int v = (t < nb) ? bsum[t] : 0;
  s[t] = v;
  __syncthreads();
  #pragma unroll
  for (int off = 1; off < 256; off <<= 1) {
    int tv = (t >= off) ? s[t - off] : 0;
    __syncthreads();
    s[t] += tv;
    __syncthreads();
  }
  if (t < nb) bsum[t] = s[t] - v;  // exclusive
}

__global__ __launch_bounds__(256) void scan3_kernel(
    const int* __restrict__ excl, const int* __restrict__ bsum,
    int* __restrict__ start, int* __restrict__ cur, int n) {
  int i = blockIdx.x * 256 + threadIdx.x;
  if (i < n) {
    int v = excl[i] + bsum[blockIdx.x];
    start[i] = v;
    cur[i] = v;
  }
}

__global__ __launch_bounds__(256) void scatter_kernel(
    const int* __restrict__ edge_src, int* __restrict__ cur,
    int* __restrict__ els, int E) {
  int e = blockIdx.x * 256 + threadIdx.x;
  if (e < E) {
    int pos = atomicAdd(&cur[edge_src[e]], 1);
    els[pos] = e;
  }
}

// ---------------- weight prep (bf16 MFMA fragments) ----------------
__global__ __launch_bounds__(256) void prep_kernel(
    const float* __restrict__ W2, const float* __restrict__ W1,
    const float* __restrict__ b2, unsigned short* __restrict__ W2p,
    unsigned short* __restrict__ W1p, float* __restrict__ b2p)
{
  int gid = blockIdx.x * 256 + threadIdx.x;
  const int NW2 = NT_TOT * 3 * 64;
  const int NW1 = 18 * 64;
  if (gid < NW2) {
    int tile = gid >> 6, ln = gid & 63;
    int nt = tile / 3, s = tile - nt * 3;
    int J = nt * 16 + (ln & 15);
    int jo = perm_col(J);
    int kbase = s * 32 + ((ln >> 4) << 3);
    #pragma unroll
    for (int j = 0; j < 8; ++j)
      W2p[(size_t)gid * 8 + j] = f2bf(W2[(kbase + j) * WNUM + jo]);
  } else if (gid < NW2 + NW1) {
    int g = gid - NW2;
    int tile = g >> 6, ln = g & 63;
    int nt = tile / 3, s = tile - nt * 3;
    int col = nt * 16 + (ln & 15);
    int kbase = s * 32 + ((ln >> 4) << 3);
    #pragma unroll
    for (int j = 0; j < 8; ++j)
      W1p[(size_t)g * 8 + j] = f2bf(W1[(kbase + j) * HID + col]);
  } else if (gid < NW2 + NW1 + WNUM) {
    int J = gid - (NW2 + NW1);
    b2p[J] = b2[perm_col(J)];
  }
}

// K1: h = relu(edge_attr @ W1 + b1) in bf16 via MFMA. 64 edges/block, 4 waves.
__global__ __launch_bounds__(256) void gemm1_mfma(
    const float* __restrict__ A, const unsigned short* __restrict__ W1p,
    const float* __restrict__ b1, unsigned short* __restrict__ h)
{
  const int tid = threadIdx.x, ln = tid & 63, wv = tid >> 6;
  const int e0 = blockIdx.x * 64;
  const int row = e0 + wv * 16 + (ln & 15);
  short8 af[3];
  #pragma unroll
  for (int s = 0; s < 3; ++s) {
    const float* p = A + (size_t)row * HID + s * 32 + ((ln >> 4) << 3);
    short8 v;
    #pragma unroll
    for (int j = 0; j < 8; ++j) v[j] = (short)f2bf(p[j]);
    af[s] = v;
  }
  #pragma unroll
  for (int nt = 0; nt < 6; ++nt) {
    f32x4 acc = {0.f, 0.f, 0.f, 0.f};
    #pragma unroll
    for (int s = 0; s < 3; ++s) {
      short8 bfr = *(const short8*)(W1p + ((size_t)(nt * 3 + s) * 64 + ln) * 8);
      acc = __builtin_amdgcn_mfma_f32_16x16x32_bf16(af[s], bfr, acc, 0, 0, 0);
    }
    int col = nt * 16 + (ln & 15);
    float bb = b1[col];
    #pragma unroll
    for (int r = 0; r < 4; ++r) {
      float v = fmaxf(acc[r] + bb, 0.f);
      int er = e0 + wv * 16 + ((ln >> 4) << 2) + r;
      h[(size_t)er * HID + col] = f2bf(v);
    }
  }
}

// K2: fused  w = h@W2+b2 (MFMA, f32 LDS double-buffer, 1 barrier/chunk)
//     schedule: prefetch(ch+1) -> TP(ch) -> MFMA(ch+1) -> epilogue -> barrier
__global__ __launch_bounds__(512, 2) void fused_mfma(
    const unsigned short* __restrict__ h, const unsigned short* __restrict__ W2p,
    const float* __restrict__ b2p, const float* __restrict__ node_attr,
    const float* __restrict__ edge_sh, const int* __restrict__ edge_dst,
    float* __restrict__ tpg)
{
  __shared__ __align__(16) float ws[2][EPB][212];  // 108.5 KB double buffer
  __shared__ float x0s[EPB][32];
  __shared__ float x1s[EPB][3][8];
  __shared__ float crs[EPB][3][8];
  __shared__ float dsu[EPB][8];
  __shared__ float sh1s[EPB][3];
  __shared__ float s0s[EPB];
  __shared__ int   dsts[EPB];

  const int tid = threadIdx.x;
  const int e0 = blockIdx.x * EPB;

  if (tid < EPB) {
    dsts[tid] = edge_dst[e0 + tid];
    s0s[tid] = edge_sh[(size_t)(e0 + tid) * 4];
  }
  if (tid >= 128 && tid < 128 + EPB * 3) {
    int i = tid - 128, e = i / 3, m = i - e * 3;
    sh1s[e][m] = edge_sh[(size_t)(e0 + e) * 4 + 1 + m];
  }
  __syncthreads();

  for (int idx = tid; idx < EPB * NA_DIM; idx += 512) {
    int e = idx / NA_DIM, c = idx - e * NA_DIM;
    float v = node_attr[(size_t)dsts[e] * NA_DIM + c];
    if (c < 32) x0s[e][c] = v;
    else { int q = c - 32; x1s[e][q % 3][q / 3] = v; }
  }
  __syncthreads();

  { // per-(e,u) derived quantities; 512 = 64*8 exact
    int e = tid >> 3, u = tid & 7;
    float a0 = x1s[e][0][u], a1 = x1s[e][1][u], a2 = x1s[e][2][u];
    float b0 = sh1s[e][0], b1v = sh1s[e][1], b2v = sh1s[e][2];
    dsu[e][u] = a0 * b0 + a1 * b1v + a2 * b2v;
    crs[e][0][u] = a1 * b2v - a2 * b1v;
    crs[e][1][u] = a2 * b0 - a0 * b2v;
    crs[e][2][u] = a0 * b1v - a1 * b0;
  }

  const int ln = tid & 63, wv = tid >> 6;
  const int c16 = ln & 15, q4 = (ln >> 4) << 2;
  short8 af[4][3];
  #pragma unroll
  for (int mt = 0; mt < 4; ++mt)
    #pragma unroll
    for (int s = 0; s < 3; ++s)
      af[mt][s] = *(const short8*)(h + (size_t)(e0 + mt * 16 + c16) * HID
                                     + s * 32 + ((ln >> 4) << 3));

  // wave tiles: tile0 = wv (always, l<128); tile1 = wv+8 (waves 0..4, l>=128)
  const bool has1 = wv < (NTC - 8);
  const int l0 = wv * 16 + c16;
  const int pc0 = (l0 & 96) | ((l0 + ((l0 >> 5) << 2)) & 31);  // w1-region swizzle
  short8 bfr0[3], bfr1[3];
  float bias0 = 0.f, bias1 = 0.f;

  auto prefetch = [&](int cc) {  // global loads only, no waits forced here
    bias0 = b2p[cc * CHW + l0];
    int nt = cc * NTC + wv;
    #pragma unroll
    for (int s = 0; s < 3; ++s)
      bfr0[s] = *(const short8*)(W2p + ((size_t)(nt * 3 + s) * 64 + ln) * 8);
    if (has1) {
      bias1 = b2p[cc * CHW + l0 + 128];
      int nt1 = cc * NTC + wv + 8;
      #pragma unroll
      for (int s = 0; s < 3; ++s)
        bfr1[s] = *(const short8*)(W2p + ((size_t)(nt1 * 3 + s) * 64 + ln) * 8);
    }
  };
  auto mfma_epilogue = [&](float (*wsd)[212]) {  // consume prefetched regs
    f32x4 acc0 = {0.f, 0.f, 0.f, 0.f}, acc0b = {0.f, 0.f, 0.f, 0.f},
          acc0c = {0.f, 0.f, 0.f, 0.f}, acc0d = {0.f, 0.f, 0.f, 0.f};
    #pragma unroll
    for (int s = 0; s < 3; ++s) {
      acc0  = __builtin_amdgcn_mfma_f32_16x16x32_bf16(af[0][s], bfr0[s], acc0, 0, 0, 0);
      acc0b = __builtin_amdgcn_mfma_f32_16x16x32_bf16(af[1][s], bfr0[s], acc0b, 0, 0, 0);
      acc0c = __builtin_amdgcn_mfma_f32_16x16x32_bf16(af[2][s], bfr0[s], acc0c, 0, 0, 0);
      acc0d = __builtin_amdgcn_mfma_f32_16x16x32_bf16(af[3][s], bfr0[s], acc0d, 0, 0, 0);
    }
    #pragma unroll
    for (int r = 0; r < 4; ++r) {
      wsd[q4 + r][pc0]      = acc0[r]  + bias0;
      wsd[16 + q4 + r][pc0] = acc0b[r] + bias0;
      wsd[32 + q4 + r][pc0] = acc0c[r] + bias0;
      wsd[48 + q4 + r][pc0] = acc0d[r] + bias0;
    }
    if (has1) {
      f32x4 a1 = {0.f, 0.f, 0.f, 0.f}, a1b = {0.f, 0.f, 0.f, 0.f},
            a1c = {0.f, 0.f, 0.f, 0.f}, a1d = {0.f, 0.f, 0.f, 0.f};
      #pragma unroll
      for (int s = 0; s < 3; ++s) {
        a1  = __builtin_amdgcn_mfma_f32_16x16x32_bf16(af[0][s], bfr1[s], a1, 0, 0, 0);
        a1b = __builtin_amdgcn_mfma_f32_16x16x32_bf16(af[1][s], bfr1[s], a1b, 0, 0, 0);
        a1c = __builtin_amdgcn_mfma_f32_16x16x32_bf16(af[2][s], bfr1[s], a1c, 0, 0, 0);
        a1d = __builtin_amdgcn_mfma_f32_16x16x32_bf16(af[3][s], bfr1[s], a1d, 0, 0, 0);
      }
      #pragma unroll
      for (int r = 0; r < 4; ++r) {
        wsd[q4 + r][l0 + 128]      = a1[r]  + bias1;
        wsd[16 + q4 + r][l0 + 128] = a1b[r] + bias1;
        wsd[32 + q4 + r][l0 + 128] = a1c[r] + bias1;
        wsd[48 + q4 + r][l0 + 128] = a1d[r] + bias1;
      }
    }
  };

  // prologue: fill buffer 0
  prefetch(0);
  mfma_epilogue(ws[0]);
  __syncthreads();

  const int e = tid >> 3, tt = tid & 7;
  const float s0 = s0s[e];
  float* tpr = tpg + (size_t)(e0 + e) * OUT_DIM;

  // hold x0 row in registers across all chunks (reused 8x)
  f32x4 x0r[8];
  #pragma unroll
  for (int i = 0; i < 8; ++i) x0r[i] = *(const f32x4*)&x0s[e][i * 4];

  for (int ch = 0; ch < NCH; ++ch) {
    if (ch + 1 < NCH) prefetch(ch + 1);   // L2 latency hides under TP below
    const float (*wsr)[212] = ws[ch & 1];

    if (tt < 4) {
      f32x4 a4 = {0.f, 0.f, 0.f, 0.f};
      #pragma unroll
      for (int u0 = 0; u0 < 32; u0 += 4) {
        int pu = (u0 + (tt << 2)) & 31;   // swizzled LDS col of logical u0
        f32x4 wq = *(const f32x4*)&wsr[e][(tt << 5) + pu];
        a4 += wq * x0r[u0 >> 2];
      }
      f32x4 d4 = {0.f, 0.f, 0.f, 0.f};
      #pragma unroll
      for (int u0 = 0; u0 < 8; u0 += 4) {
        f32x4 wq = *(const f32x4*)&wsr[e][168 + (tt << 3) + u0];
        f32x4 dq = *(const f32x4*)&dsu[e][u0];
        d4 += wq * dq;
      }
      float sum1 = (a4[0] + a4[1]) + (a4[2] + a4[3]);
      float sum2 = (d4[0] + d4[1]) + (d4[2] + d4[3]);
      tpr[4 * ch + tt] = N0f * (s0 * sum1 + INV_S3 * sum2);
    } else if (tt < 7) {
      const int m = tt - 4;
      f32x4 a4 = {0.f, 0.f, 0.f, 0.f};
      #pragma unroll
      for (int u0 = 0; u0 < 32; u0 += 4) {
        f32x4 wq = *(const f32x4*)&wsr[e][128 + u0];
        a4 += wq * x0r[u0 >> 2];
      }
      f32x4 b4 = {0.f, 0.f, 0.f, 0.f};
      #pragma unroll
      for (int u0 = 0; u0 < 8; u0 += 4) {
        f32x4 wq = *(const f32x4*)&wsr[e][160 + u0];
        f32x4 xq = *(const f32x4*)&x1s[e][m][u0];
        b4 += wq * xq;
      }
      float sum1 = (a4[0] + a4[1]) + (a4[2] + a4[3]);
      float sum2 = (b4[0] + b4[1]) + (b4[2] + b4[3]);
      tpr[32 + ch * 3 + m] = N0f * (sh1s[e][m] * sum1 + s0 * sum2);
    } else {
      #pragma unroll
      for (int m = 0; m < 3; ++m) {
        f32x4 c4 = {0.f, 0.f, 0.f, 0.f};
        #pragma unroll
        for (int u0 = 0; u0 < 8; u0 += 4) {
          f32x4 wq = *(const f32x4*)&wsr[e][200 + u0];
          f32x4 cq = *(const f32x4*)&crs[e][m][u0];
          c4 += wq * cq;
        }
        tpr[56 + ch * 3 + m] = C_OUT1E * ((c4[0] + c4[1]) + (c4[2] + c4[3]));
      }
    }

    __builtin_amdgcn_sched_barrier(0);    // TP fully issued before MFMA waits
    if (ch + 1 < NCH) mfma_epilogue(ws[(ch + 1) & 1]);  // other buffer: no WAR
    __syncthreads();                      // single barrier per chunk
  }
}

// K3: per-node mean over sorted edge lists (no atomics)
__global__ __launch_bounds__(256) void gather_kernel(
    const float* __restrict__ tp, const int* __restrict__ els,
    const int* __restrict__ start, const int* __restrict__ hist,
    float* __restrict__ out, int total)
{
  int idx = blockIdx.x * 256 + threadIdx.x;
  if (idx >= total) return;
  int node = idx / OUT_DIM, o = idx - node * OUT_DIM;
  int s = start[node], c = hist[node];
  float sum = 0.f;
  for (int i = 0; i < c; ++i)
    sum += tp[(size_t)els[s + i] * OUT_DIM + o];
  out[idx] = sum / (float)(c > 0 ? c : 1);
}

extern "C" void kernel_launch(void* const* d_in, const int* in_sizes, int n_in,
                              void* d_out, int out_size, void* d_ws, size_t ws_size,
                              hipStream_t stream) {
  const float* node_attr = (const float*)d_in[0];
  const float* edge_attr = (const float*)d_in[1];
  const float* edge_sh   = (const float*)d_in[2];
  const float* W1        = (const float*)d_in[3];
  const float* b1        = (const float*)d_in[4];
  const float* W2        = (const float*)d_in[5];
  const float* b2        = (const float*)d_in[6];
  const int*   edge_src  = (const int*)d_in[7];
  const int*   edge_dst  = (const int*)d_in[8];
  float* out = (float*)d_out;

  const int E = in_sizes[7];
  const int N = in_sizes[0] / NA_DIM;

  char* wsb = (char*)d_ws;
  int*   hist  = (int*)(wsb + 0x000000);          // 40000 ints
  int*   excl  = (int*)(wsb + 0x040000);
  int*   start = (int*)(wsb + 0x080000);
  int*   cur   = (int*)(wsb + 0x0C0000);
  int*   bsum  = (int*)(wsb + 0x100000);          // 256 ints
  int*   els   = (int*)(wsb + 0x110000);          // 120000 ints
  unsigned short* W2p = (unsigned short*)(wsb + 0x200000);   // 320 KB
  unsigned short* W1p = (unsigned short*)(wsb + 0x280000);
  float*          b2p = (float*)(wsb + 0x2C0000);
  unsigned short* hbf = (unsigned short*)(wsb + 0x300000);   // 23 MB
  float*          tpg = (float*)(wsb + 0x1C00000);           // 38.4 MB

  const int NB = (N + 255) / 256;  // 157

  zero_int_kernel<<<NB, 256, 0, stream>>>(hist, N);
  hist_kernel<<<(E + 255) / 256, 256, 0, stream>>>(edge_src, hist, E);
  scan1_kernel<<<NB, 256, 0, stream>>>(hist, excl, bsum, N);
  scan2_kernel<<<1, 256, 0, stream>>>(bsum, NB);
  scan3_kernel<<<NB, 256, 0, stream>>>(excl, bsum, start, cur, N);
  scatter_kernel<<<(E + 255) / 256, 256, 0, stream>>>(edge_src, cur, els, E);

  const int prep_total = NT_TOT * 3 * 64 + 18 * 64 + WNUM;
  prep_kernel<<<(prep_total + 255) / 256, 256, 0, stream>>>(W2, W1, b2, W2p, W1p, b2p);

  gemm1_mfma<<<E / 64, 256, 0, stream>>>(edge_attr, W1p, b1, hbf);
  fused_mfma<<<E / EPB, 512, 0, stream>>>(hbf, W2p, b2p, node_attr, edge_sh,
                                          edge_dst, tpg);
  gather_kernel<<<(N * OUT_DIM + 255) / 256, 256, 0, stream>>>(
      tpg, els, start, hist, out, N * OUT_DIM);
}